// Round 6
// baseline (204.133 us; speedup 1.0000x reference)
//
#include <hip/hip_runtime.h>

// B=2, T=2048, C=1024, H=16, DQK=DV=64. Inputs fp32, output fp32, bf16 MFMA inside.

typedef short bf16x4 __attribute__((ext_vector_type(4)));
typedef short bf16x8 __attribute__((ext_vector_type(8)));
typedef float f32x4 __attribute__((ext_vector_type(4)));

#define MFMA_BF16 __builtin_amdgcn_mfma_f32_16x16x32_bf16

// log2(e)/8: Q pre-scale so softmax runs in base-2 domain (exp2 = bare v_exp_f32)
#define QSCALE 0.18033688011112042f

__device__ __forceinline__ unsigned short f2bf(float f) {
    union { float f; unsigned u; } un; un.f = f;
    unsigned r = un.u + 0x7fffu + ((un.u >> 16) & 1u);  // RNE
    return (unsigned short)(r >> 16);
}
__device__ __forceinline__ unsigned pk2(float a, float b) {
    return (unsigned)f2bf(a) | ((unsigned)f2bf(b) << 16);
}
// truncating pack of two floats into packed bf16x2: one v_perm_b32 (R19)
__device__ __forceinline__ unsigned pk2t(float a, float b) {
    union { float f; unsigned u; } ua, ub; ua.f = a; ub.f = b;
    return __builtin_amdgcn_perm(ub.u, ua.u, 0x07060302u);
}
__device__ __forceinline__ void gload16(const void* g, void* l) {
    __builtin_amdgcn_global_load_lds(
        (const __attribute__((address_space(1))) unsigned int*)g,
        (__attribute__((address_space(3))) unsigned int*)l, 16, 0, 0);
}

// ---------- fused prep: x/wq/wk/wv fp32->bf16, wo fp32->bf16 transposed ----------
__global__ __launch_bounds__(256) void prep(
    const float* __restrict__ x, const float* __restrict__ wq,
    const float* __restrict__ wk, const float* __restrict__ wv,
    const float* __restrict__ wo,
    unsigned short* __restrict__ x16, unsigned short* __restrict__ wq16,
    unsigned short* __restrict__ wk16, unsigned short* __restrict__ wv16,
    unsigned short* __restrict__ wot)
{
    const int bid = blockIdx.x;
    if (bid < 3584) {
        const float* s; unsigned short* d; int off;
        if (bid < 2048)      { s = x;  d = x16;  off = bid * 2048; }
        else if (bid < 2560) { s = wq; d = wq16; off = (bid - 2048) * 2048; }
        else if (bid < 3072) { s = wk; d = wk16; off = (bid - 2560) * 2048; }
        else                 { s = wv; d = wv16; off = (bid - 3072) * 2048; }
        int i = off + threadIdx.x * 8;
        float4 f0 = *(const float4*)&s[i], f1 = *(const float4*)&s[i + 4];
        uint4 o;
        o.x = pk2(f0.x, f0.y); o.y = pk2(f0.z, f0.w);
        o.z = pk2(f1.x, f1.y); o.w = pk2(f1.z, f1.w);
        *(uint4*)&d[i] = o;
    } else {
        // wo [K=1024][N=1024] -> wot [N][K] bf16
        __shared__ unsigned short t[64 * 72];
        const int b2 = bid - 3584;
        const int k0 = (b2 & 15) << 6, n0 = (b2 >> 4) << 6;
        const int r = threadIdx.x >> 2, cg = (threadIdx.x & 3) << 4;
        const float* src = &wo[(k0 + r) * 1024 + n0 + cg];
        #pragma unroll
        for (int j = 0; j < 16; j += 4) {
            float4 f = *(const float4*)&src[j];
            t[(cg + j + 0) * 72 + r] = f2bf(f.x);
            t[(cg + j + 1) * 72 + r] = f2bf(f.y);
            t[(cg + j + 2) * 72 + r] = f2bf(f.z);
            t[(cg + j + 3) * 72 + r] = f2bf(f.w);
        }
        __syncthreads();
        unsigned short* dst = &wot[(n0 + r) * 1024 + k0 + cg];
        unsigned short* tr = &t[r * 72 + cg];
        unsigned v[16];
        #pragma unroll
        for (int j = 0; j < 16; ++j) v[j] = tr[j];
        uint4 o0, o1;
        o0.x = v[0] | (v[1] << 16);   o0.y = v[2] | (v[3] << 16);
        o0.z = v[4] | (v[5] << 16);   o0.w = v[6] | (v[7] << 16);
        o1.x = v[8] | (v[9] << 16);   o1.y = v[10] | (v[11] << 16);
        o1.z = v[12] | (v[13] << 16); o1.w = v[14] | (v[15] << 16);
        *(uint4*)&dst[0] = o0;
        *(uint4*)&dst[8] = o1;
    }
}

// ---------- 128x128 bf16 GEMM, K=1024: BK=32 dbuf gload16, fully unrolled ----------
// R16 data-side XOR bank swizzle (validated): G-chunk = (lane&3) ^ ((r16>>1)&3);
// readers use chunk l4 ^ ((l15>>1)&3). mode 2 = vtb store with sigma permutation.
__device__ __forceinline__ void gemm_body(
    const unsigned short* __restrict__ A, const unsigned short* __restrict__ Bm,
    void* __restrict__ C, int m0, int n0, int mode, int ldc, float sc)
{
    __shared__ unsigned short sa[2][128 * 32];
    __shared__ unsigned short sb[2][128 * 32];
    const int tid = threadIdx.x, wave = tid >> 6, lane = tid & 63;
    const int l15 = lane & 15, l4 = lane >> 4;
    const int wm = (wave >> 1) << 6, wn = (wave & 1) << 6;

    const int r16 = lane >> 2;                               // 0..15
    const int gcol = (((lane & 3) ^ ((r16 >> 1) & 3)) << 3); // swizzled 16B chunk
    const int rcol = (l4 ^ ((l15 >> 1) & 3)) << 3;           // read-side chunk
    const unsigned short* Ag0 = &A[(size_t)(m0 + wave * 16 + r16) * 1024 + gcol];
    const unsigned short* Ag1 = Ag0 + (size_t)64 * 1024;
    const unsigned short* Bg0 = &Bm[(size_t)(n0 + wave * 16 + r16) * 1024 + gcol];
    const unsigned short* Bg1 = Bg0 + (size_t)64 * 1024;
    const int lb0 = (wave * 16) * 32;      // wave-uniform LDS bases (elements)
    const int lb1 = (64 + wave * 16) * 32;

    gload16(Ag0, &sa[0][lb0]);
    gload16(Ag1, &sa[0][lb1]);
    gload16(Bg0, &sb[0][lb0]);
    gload16(Bg1, &sb[0][lb1]);
    __syncthreads();

    f32x4 acc[4][4] = {};

    #pragma unroll
    for (int kk = 0; kk < 32; ++kk) {
        const int cur = kk & 1;
        if (kk < 31) {
            const int off = (kk + 1) * 32;
            const int nxt = 1 - cur;
            gload16(Ag0 + off, &sa[nxt][lb0]);
            gload16(Ag1 + off, &sa[nxt][lb1]);
            gload16(Bg0 + off, &sb[nxt][lb0]);
            gload16(Bg1 + off, &sb[nxt][lb1]);
        }
        bf16x8 af[4], bf4[4];
        #pragma unroll
        for (int i = 0; i < 4; ++i)
            af[i] = *(const bf16x8*)&sa[cur][(wm + i * 16 + l15) * 32 + rcol];
        #pragma unroll
        for (int j = 0; j < 4; ++j)
            bf4[j] = *(const bf16x8*)&sb[cur][(wn + j * 16 + l15) * 32 + rcol];
        #pragma unroll
        for (int i = 0; i < 4; ++i)
            #pragma unroll
            for (int j = 0; j < 4; ++j)
                acc[i][j] = MFMA_BF16(af[i], bf4[j], acc[i][j], 0, 0, 0);
        __syncthreads();   // next-slab loads have flown during the MFMAs above
    }

    #pragma unroll
    for (int i = 0; i < 4; ++i)
        #pragma unroll
        for (int j = 0; j < 4; ++j)
            #pragma unroll
            for (int r = 0; r < 4; ++r) {
                int row = m0 + wm + i * 16 + l4 * 4 + r;
                int col = n0 + wn + j * 16 + l15;
                float val = acc[i][j][r];
                if (mode == 0) {
                    int nb = row >> 11, t = row & 2047;
                    int hh = col >> 6, dd = col & 63;
                    ((unsigned short*)C)[(((nb << 4) + hh) * 2048 + t) * 64 + dd] =
                        f2bf(val * sc);
                } else if (mode == 1) {
                    ((float*)C)[(size_t)row * ldc + col] = val;
                } else {
                    // sigma permutation within each 32-col block (see R15)
                    int s = col & 31;
                    int cp = (col & ~31) | (((s >> 2) & 3) << 3)
                                         | (((s >> 4) & 1) << 2) | (s & 3);
                    ((unsigned short*)C)[(size_t)row * ldc + cp] = f2bf(val);
                }
            }
}

// grid 768: [0,512) QK fused | [512,768) V^T = Wv @ X^T (sigma-permuted cols)
__global__ __launch_bounds__(256) void proj(
    const unsigned short* __restrict__ x16,
    const unsigned short* __restrict__ wq16,
    const unsigned short* __restrict__ wk16,
    const unsigned short* __restrict__ wv16,
    unsigned short* __restrict__ qbuf,
    unsigned short* __restrict__ kbuf,
    unsigned short* __restrict__ vtb)
{
    const int bid = blockIdx.x;
    if (bid < 512) {
        int m0 = (bid & 31) << 7;
        int n0g = (bid >> 5) << 7;
        if (n0g < 1024)
            gemm_body(x16, wq16, qbuf, m0, n0g, 0, 0, QSCALE);
        else
            gemm_body(x16, wk16, kbuf, m0, n0g - 1024, 0, 0, 1.0f);
    } else {
        int v = bid - 512;
        gemm_body(wv16, x16, vtb, (v & 7) << 7, (v >> 3) << 7, 2, 4096, 1.0f);
    }
}

// ---------- out = Y @ Wo^T: 128x128 gemm_body tiles, grid 256 (R17 best) ----------
__global__ __launch_bounds__(256) void outp(
    const unsigned short* __restrict__ ybuf,
    const unsigned short* __restrict__ wot,
    float* __restrict__ out)
{
    const int bid = blockIdx.x;
    gemm_body(ybuf, wot, out, (bid & 31) << 7, (bid >> 5) << 7, 1, 1024, 1.0f);
}

// ---------- flash causal attention: 64-row paired tiles, split-K, V-direct (R22) ----------
// R21 post-mortem: OccupancyPercent ~25% (R4) = ONE 512-thread block/CU even
// though 2x64KB LDS should fit -> LDS capacity/granularity blocks co-residency.
// R22: eliminate the V LDS staging. The LDS chunk swizzle provably cancels
// (write G[r][c^s], read [c^s]), so V fragments are straight global 16B chunks
// at col ks*32+l4*8 of the sigma-permuted vtb. Gather them global->VGPR at the
// top of each superstep (consumed in PV ~400+cyc later; vtb is L2/L3-resident,
// FETCH has been 12MB all along). LDS 64->32KB per block -> 2 blocks/CU
// (4 waves/SIMD), lighter barrier drain (2 gload16/ss instead of 4), 8 fewer
// ds_reads/ss. Identical bytes reach identical MFMA operands -> same numerics.
__global__ __launch_bounds__(512, 4) void attn(
    const unsigned short* __restrict__ q,
    const unsigned short* __restrict__ k,
    const unsigned short* __restrict__ vt,
    unsigned short* __restrict__ y)
{
    __shared__ unsigned short sk[2][2][64 * 64];   // [stage][parity][s][d], 32 KB
    const int tid = threadIdx.x, wave = tid >> 6, lane = tid & 63;
    const int ws = wave & 3, wk2 = wave >> 2;      // row-slice, k-parity
    const int l15 = lane & 15, l4 = lane >> 4;
    const int bid = blockIdx.x;
    const int pr = bid >> 5;                       // 0..15 (pair index)
    const int bh = bid & 31;
    const int nb = bh >> 4, hh = bh & 15;
    const size_t base = (size_t)bh << 17;

    // staging: 8 waves x 8 rows cover all 64 rows of a tile in ONE gload16 call
    const int lrow = lane >> 3;                           // 0..7 local row
    const int gch = ((lane & 7) ^ lrow) << 3;             // swizzled chunk (elems)
    const int row = wave * 8 + lrow;                      // 0..63
    const unsigned short* kg = &k[base + (size_t)row * 64 + gch];
    const int lb = (wave * 8) * 64;                       // wave-uniform LDS base

    // V-direct fragment base: row (hh*64 + ds*16 + l15), col (nb*2048 + l4*8);
    // fragment (ds,ks) of k-tile st adds ds*16*4096 + st*64 + ks*32.
    const unsigned short* vbase =
        &vt[(size_t)((hh << 6) + l15) * 4096 + (nb << 11) + (l4 << 3)];

    // read-side swizzled chunk offset for kf (elements)
    const int rch0 = ((0 + l4) ^ (l15 & 7)) << 3;   // ks=0
    const int rch1 = ((4 + l4) ^ (l15 & 7)) << 3;   // ks=1

    // merge scratch views over the (then-dead) K staging buffer
    float* mrg = (float*)&sk[0][0][0];              // 4096 floats = 16 KB
    float* lsr = (float*)&sk[1][0][0];
    const int mslot = (ws << 6) + lane;             // 0..255
    const int mb = mslot << 4;                      // 16 floats/thread

    auto process = [&](const int t) {
        const int q0 = t << 6;
        // Q fragments (B-operand: n=l15 -> q row, k=l4*8..+7 -> d)
        bf16x8 qf[2];
        #pragma unroll
        for (int ks = 0; ks < 2; ++ks)
            qf[ks] = *(const bf16x8*)
                &q[base + (size_t)(q0 + ws * 16 + l15) * 64 + ks * 32 + l4 * 8];

        float l_sum = 0.f;
        f32x4 acc[4] = {};
        const int nsup = (t >> 1) + 1;              // supersteps for this tile

        auto stage_pair = [&](const int sbuf, const int p) {
            gload16(kg + ((size_t)p << 13), &sk[sbuf][0][lb]);   // k-tile 2p
            if (2 * p + 1 <= t)                                  // k-tile 2p+1
                gload16(kg + ((size_t)p << 13) + 4096, &sk[sbuf][1][lb]);
        };

        stage_pair(0, 0);
        __syncthreads();

        // superstep body; LITERAL cur at call sites so LDS bases fold to imms
        auto sstep = [&](const int cur, const int p) {
            if (p + 1 < nsup) stage_pair(cur ^ 1, p + 1);
            const int st = 2 * p + wk2;
            if (st <= t) {                           // wave-uniform predicate
                // V fragments for THIS tile: issue now, consume in PV (~400cyc)
                bf16x8 vf[2][4];
                #pragma unroll
                for (int ks = 0; ks < 2; ++ks)
                    #pragma unroll
                    for (int ds = 0; ds < 4; ++ds)
                        vf[ks][ds] = *(const bf16x8*)
                            &vbase[(ds << 16) + (st << 6) + (ks << 5)];

                const unsigned short* skc = &sk[cur][wk2][0];

                f32x4 s_acc[4] = {};
                #pragma unroll
                for (int ns = 0; ns < 4; ++ns) {
                    bf16x8 kf0 = *(const bf16x8*)&skc[(ns * 16 + l15) * 64 + rch0];
                    bf16x8 kf1 = *(const bf16x8*)&skc[(ns * 16 + l15) * 64 + rch1];
                    s_acc[ns] = MFMA_BF16(kf0, qf[0], s_acc[ns], 0, 0, 0);
                    s_acc[ns] = MFMA_BF16(kf1, qf[1], s_acc[ns], 0, 0, 0);
                }

                // causal mask: only the diagonal k-tile (st == t) intersects
                if (st == t) {
                    const int ql = ws * 16 + l15;
                    #pragma unroll
                    for (int ns = 0; ns < 4; ++ns)
                        #pragma unroll
                        for (int r = 0; r < 4; ++r)
                            if (ns * 16 + l4 * 4 + r > ql) s_acc[ns][r] = -1e30f;
                }

                float pe[4][4];
                #pragma unroll
                for (int ns = 0; ns < 4; ++ns) {
                    #pragma unroll
                    for (int r = 0; r < 4; ++r) pe[ns][r] = exp2f(s_acc[ns][r]);
                    l_sum += (pe[ns][0] + pe[ns][1]) + (pe[ns][2] + pe[ns][3]);
                }

                #pragma unroll
                for (int ks = 0; ks < 2; ++ks) {
                    uint4 pw;
                    pw.x = pk2t(pe[2 * ks][0], pe[2 * ks][1]);
                    pw.y = pk2t(pe[2 * ks][2], pe[2 * ks][3]);
                    pw.z = pk2t(pe[2 * ks + 1][0], pe[2 * ks + 1][1]);
                    pw.w = pk2t(pe[2 * ks + 1][2], pe[2 * ks + 1][3]);
                    bf16x8 pf = *(bf16x8*)&pw;
                    #pragma unroll
                    for (int ds = 0; ds < 4; ++ds)
                        acc[ds] = MFMA_BF16(vf[ks][ds], pf, acc[ds], 0, 0, 0);
                }
            }
            __syncthreads();   // next pair's gload16 deposits flew during compute
        };

        int p = 0;
        for (; p + 2 <= nsup; p += 2) { sstep(0, p); sstep(1, p + 1); }
        if (p < nsup) sstep(0, p);

        // ---- cross-parity merge through LDS (exact f32 adds) ----
        if (wk2 == 1) {
            #pragma unroll
            for (int ds = 0; ds < 4; ++ds)
                *(f32x4*)&mrg[mb + ((ds ^ (lane & 3)) << 2)] = acc[ds];
            lsr[mslot] = l_sum;
        }
        __syncthreads();
        if (wk2 == 0) {
            #pragma unroll
            for (int ds = 0; ds < 4; ++ds)
                acc[ds] += *(const f32x4*)&mrg[mb + ((ds ^ (lane & 3)) << 2)];
            l_sum += lsr[mslot];

            float ls = l_sum;
            ls += __shfl_xor(ls, 16);
            ls += __shfl_xor(ls, 32);
            const float rl = __builtin_amdgcn_rcpf(ls);

            const size_t rowbase =
                ((size_t)((nb << 11) + q0 + ws * 16 + l15) << 10) + (hh << 6) + l4 * 4;
            #pragma unroll
            for (int ds = 0; ds < 4; ++ds) {
                uint2 o;
                o.x = pk2(acc[ds][0] * rl, acc[ds][1] * rl);
                o.y = pk2(acc[ds][2] * rl, acc[ds][3] * rl);
                *(uint2*)&y[rowbase + ds * 16] = o;
            }
        }
        __syncthreads();   // merge reads done before next tile's staging reuses LDS
    };

    process(31 - pr);   // heavy tile first
    process(pr);        // complement: total supersteps = 17 for every block
}

extern "C" void kernel_launch(void* const* d_in, const int* in_sizes, int n_in,
                              void* d_out, int out_size, void* d_ws, size_t ws_size,
                              hipStream_t stream) {
    const float* x  = (const float*)d_in[0];
    const float* wq = (const float*)d_in[1];
    const float* wk = (const float*)d_in[2];
    const float* wv = (const float*)d_in[3];
    const float* wo = (const float*)d_in[4];
    float* out = (float*)d_out;

    const size_t M1 = 1u << 20;
    unsigned short* x16  = (unsigned short*)d_ws;          // 4M
    unsigned short* wq16 = x16 + 4 * M1;                   // 1M
    unsigned short* wk16 = wq16 + M1;
    unsigned short* wv16 = wk16 + M1;
    unsigned short* wot  = wv16 + M1;                      // 1M
    unsigned short* qbuf = wot + M1;                       // 4M [B,H,T,64]
    unsigned short* kbuf = qbuf + 4 * M1;                  // 4M
    unsigned short* vtb  = kbuf + 4 * M1;                  // 4M [1024][4096] sigma-perm
    unsigned short* ybuf = vtb + 4 * M1;                   // 4M [4096][1024]

    dim3 blk(256);
    prep<<<3840, blk, 0, stream>>>(x, wq, wk, wv, wo, x16, wq16, wk16, wv16, wot);
    proj<<<768, blk, 0, stream>>>(x16, wq16, wk16, wv16, qbuf, kbuf, vtb);
    attn<<<512, dim3(512), 0, stream>>>(qbuf, kbuf, vtb, ybuf);
    outp<<<256, blk, 0, stream>>>(ybuf, wot, out);
}

// Round 7
// 169.186 us; speedup vs baseline: 1.2066x; 1.2066x over previous
//
#include <hip/hip_runtime.h>

// B=2, T=2048, C=1024, H=16, DQK=DV=64. Inputs fp32, output fp32, bf16 MFMA inside.

typedef short bf16x4 __attribute__((ext_vector_type(4)));
typedef short bf16x8 __attribute__((ext_vector_type(8)));
typedef float f32x4 __attribute__((ext_vector_type(4)));

#define MFMA_BF16 __builtin_amdgcn_mfma_f32_16x16x32_bf16

// log2(e)/8: Q pre-scale so softmax runs in base-2 domain (exp2 = bare v_exp_f32)
#define QSCALE 0.18033688011112042f

__device__ __forceinline__ unsigned short f2bf(float f) {
    union { float f; unsigned u; } un; un.f = f;
    unsigned r = un.u + 0x7fffu + ((un.u >> 16) & 1u);  // RNE
    return (unsigned short)(r >> 16);
}
__device__ __forceinline__ unsigned pk2(float a, float b) {
    return (unsigned)f2bf(a) | ((unsigned)f2bf(b) << 16);
}
// truncating pack of two floats into packed bf16x2: one v_perm_b32 (R19)
__device__ __forceinline__ unsigned pk2t(float a, float b) {
    union { float f; unsigned u; } ua, ub; ua.f = a; ub.f = b;
    return __builtin_amdgcn_perm(ub.u, ua.u, 0x07060302u);
}
__device__ __forceinline__ void gload16(const void* g, void* l) {
    __builtin_amdgcn_global_load_lds(
        (const __attribute__((address_space(1))) unsigned int*)g,
        (__attribute__((address_space(3))) unsigned int*)l, 16, 0, 0);
}

// ---------- fused prep: x/wq/wk/wv fp32->bf16, wo fp32->bf16 transposed ----------
__global__ __launch_bounds__(256) void prep(
    const float* __restrict__ x, const float* __restrict__ wq,
    const float* __restrict__ wk, const float* __restrict__ wv,
    const float* __restrict__ wo,
    unsigned short* __restrict__ x16, unsigned short* __restrict__ wq16,
    unsigned short* __restrict__ wk16, unsigned short* __restrict__ wv16,
    unsigned short* __restrict__ wot)
{
    const int bid = blockIdx.x;
    if (bid < 3584) {
        const float* s; unsigned short* d; int off;
        if (bid < 2048)      { s = x;  d = x16;  off = bid * 2048; }
        else if (bid < 2560) { s = wq; d = wq16; off = (bid - 2048) * 2048; }
        else if (bid < 3072) { s = wk; d = wk16; off = (bid - 2560) * 2048; }
        else                 { s = wv; d = wv16; off = (bid - 3072) * 2048; }
        int i = off + threadIdx.x * 8;
        float4 f0 = *(const float4*)&s[i], f1 = *(const float4*)&s[i + 4];
        uint4 o;
        o.x = pk2(f0.x, f0.y); o.y = pk2(f0.z, f0.w);
        o.z = pk2(f1.x, f1.y); o.w = pk2(f1.z, f1.w);
        *(uint4*)&d[i] = o;
    } else {
        // wo [K=1024][N=1024] -> wot [N][K] bf16
        __shared__ unsigned short t[64 * 72];
        const int b2 = bid - 3584;
        const int k0 = (b2 & 15) << 6, n0 = (b2 >> 4) << 6;
        const int r = threadIdx.x >> 2, cg = (threadIdx.x & 3) << 4;
        const float* src = &wo[(k0 + r) * 1024 + n0 + cg];
        #pragma unroll
        for (int j = 0; j < 16; j += 4) {
            float4 f = *(const float4*)&src[j];
            t[(cg + j + 0) * 72 + r] = f2bf(f.x);
            t[(cg + j + 1) * 72 + r] = f2bf(f.y);
            t[(cg + j + 2) * 72 + r] = f2bf(f.z);
            t[(cg + j + 3) * 72 + r] = f2bf(f.w);
        }
        __syncthreads();
        unsigned short* dst = &wot[(n0 + r) * 1024 + k0 + cg];
        unsigned short* tr = &t[r * 72 + cg];
        unsigned v[16];
        #pragma unroll
        for (int j = 0; j < 16; ++j) v[j] = tr[j];
        uint4 o0, o1;
        o0.x = v[0] | (v[1] << 16);   o0.y = v[2] | (v[3] << 16);
        o0.z = v[4] | (v[5] << 16);   o0.w = v[6] | (v[7] << 16);
        o1.x = v[8] | (v[9] << 16);   o1.y = v[10] | (v[11] << 16);
        o1.z = v[12] | (v[13] << 16); o1.w = v[14] | (v[15] << 16);
        *(uint4*)&dst[0] = o0;
        *(uint4*)&dst[8] = o1;
    }
}

// ---------- 128x128 bf16 GEMM, K=1024: BK=32 dbuf gload16, fully unrolled ----------
// R16 data-side XOR bank swizzle (validated): G-chunk = (lane&3) ^ ((r16>>1)&3);
// readers use chunk l4 ^ ((l15>>1)&3). mode 2 = vtb store with sigma permutation.
__device__ __forceinline__ void gemm_body(
    const unsigned short* __restrict__ A, const unsigned short* __restrict__ Bm,
    void* __restrict__ C, int m0, int n0, int mode, int ldc, float sc)
{
    __shared__ unsigned short sa[2][128 * 32];
    __shared__ unsigned short sb[2][128 * 32];
    const int tid = threadIdx.x, wave = tid >> 6, lane = tid & 63;
    const int l15 = lane & 15, l4 = lane >> 4;
    const int wm = (wave >> 1) << 6, wn = (wave & 1) << 6;

    const int r16 = lane >> 2;                               // 0..15
    const int gcol = (((lane & 3) ^ ((r16 >> 1) & 3)) << 3); // swizzled 16B chunk
    const int rcol = (l4 ^ ((l15 >> 1) & 3)) << 3;           // read-side chunk
    const unsigned short* Ag0 = &A[(size_t)(m0 + wave * 16 + r16) * 1024 + gcol];
    const unsigned short* Ag1 = Ag0 + (size_t)64 * 1024;
    const unsigned short* Bg0 = &Bm[(size_t)(n0 + wave * 16 + r16) * 1024 + gcol];
    const unsigned short* Bg1 = Bg0 + (size_t)64 * 1024;
    const int lb0 = (wave * 16) * 32;      // wave-uniform LDS bases (elements)
    const int lb1 = (64 + wave * 16) * 32;

    gload16(Ag0, &sa[0][lb0]);
    gload16(Ag1, &sa[0][lb1]);
    gload16(Bg0, &sb[0][lb0]);
    gload16(Bg1, &sb[0][lb1]);
    __syncthreads();

    f32x4 acc[4][4] = {};

    #pragma unroll
    for (int kk = 0; kk < 32; ++kk) {
        const int cur = kk & 1;
        if (kk < 31) {
            const int off = (kk + 1) * 32;
            const int nxt = 1 - cur;
            gload16(Ag0 + off, &sa[nxt][lb0]);
            gload16(Ag1 + off, &sa[nxt][lb1]);
            gload16(Bg0 + off, &sb[nxt][lb0]);
            gload16(Bg1 + off, &sb[nxt][lb1]);
        }
        bf16x8 af[4], bf4[4];
        #pragma unroll
        for (int i = 0; i < 4; ++i)
            af[i] = *(const bf16x8*)&sa[cur][(wm + i * 16 + l15) * 32 + rcol];
        #pragma unroll
        for (int j = 0; j < 4; ++j)
            bf4[j] = *(const bf16x8*)&sb[cur][(wn + j * 16 + l15) * 32 + rcol];
        #pragma unroll
        for (int i = 0; i < 4; ++i)
            #pragma unroll
            for (int j = 0; j < 4; ++j)
                acc[i][j] = MFMA_BF16(af[i], bf4[j], acc[i][j], 0, 0, 0);
        __syncthreads();   // next-slab loads have flown during the MFMAs above
    }

    #pragma unroll
    for (int i = 0; i < 4; ++i)
        #pragma unroll
        for (int j = 0; j < 4; ++j)
            #pragma unroll
            for (int r = 0; r < 4; ++r) {
                int row = m0 + wm + i * 16 + l4 * 4 + r;
                int col = n0 + wn + j * 16 + l15;
                float val = acc[i][j][r];
                if (mode == 0) {
                    int nb = row >> 11, t = row & 2047;
                    int hh = col >> 6, dd = col & 63;
                    ((unsigned short*)C)[(((nb << 4) + hh) * 2048 + t) * 64 + dd] =
                        f2bf(val * sc);
                } else if (mode == 1) {
                    ((float*)C)[(size_t)row * ldc + col] = val;
                } else {
                    // sigma permutation within each 32-col block (see R15)
                    int s = col & 31;
                    int cp = (col & ~31) | (((s >> 2) & 3) << 3)
                                         | (((s >> 4) & 1) << 2) | (s & 3);
                    ((unsigned short*)C)[(size_t)row * ldc + cp] = f2bf(val);
                }
            }
}

// grid 768: [0,512) QK fused | [512,768) V^T = Wv @ X^T (sigma-permuted cols)
__global__ __launch_bounds__(256) void proj(
    const unsigned short* __restrict__ x16,
    const unsigned short* __restrict__ wq16,
    const unsigned short* __restrict__ wk16,
    const unsigned short* __restrict__ wv16,
    unsigned short* __restrict__ qbuf,
    unsigned short* __restrict__ kbuf,
    unsigned short* __restrict__ vtb)
{
    const int bid = blockIdx.x;
    if (bid < 512) {
        int m0 = (bid & 31) << 7;
        int n0g = (bid >> 5) << 7;
        if (n0g < 1024)
            gemm_body(x16, wq16, qbuf, m0, n0g, 0, 0, QSCALE);
        else
            gemm_body(x16, wk16, kbuf, m0, n0g - 1024, 0, 0, 1.0f);
    } else {
        int v = bid - 512;
        gemm_body(wv16, x16, vtb, (v & 7) << 7, (v >> 3) << 7, 2, 4096, 1.0f);
    }
}

// ---------- out = Y @ Wo^T: 128x128 gemm_body tiles, grid 256 (R17 best) ----------
__global__ __launch_bounds__(256) void outp(
    const unsigned short* __restrict__ ybuf,
    const unsigned short* __restrict__ wot,
    float* __restrict__ out)
{
    const int bid = blockIdx.x;
    gemm_body(ybuf, wot, out, (bid & 31) << 7, (bid >> 5) << 7, 1, 1024, 1.0f);
}

// ---------- flash causal attention: 128-row paired tiles, split-K, 2 q-groups (R23) ----------
// R22 post-mortem: V-direct global gather = 16 cache lines/instr, L1-path bound
// (77us). REVERTED to R21's LDS staging. Unifying model across R0-R22: the
// per-CU LDS datapath is the serial resource (~160KB/superstep at ~100B/cyc
// ~ the invariant 3000cyc/step); TLP never fixed it because every wave re-reads
// the full K/V tile for its q-slice (4x amplification).
// R23: double work per LDS byte. 128-row Q tiles, each wave covers TWO
// 16-row q-groups (g=0,1 at q0+64g+ws*16) -> every kf/vf fragment feeds 2
// MFMAs. Same 2-parity split-K, same staging, same 64KB LDS; per-superstep
// LDS traffic unchanged but covers 128q x 128kv (was 64q x 128kv).
// Tiles 0..15 paired (15-pr, pr): supersteps = (16-pr)+(pr+1) = 17 for every
// block; grid 256 = 1/CU, zero tail. Per-wave state ~ R17's 104 VGPR at
// 2 waves/SIMD (256-reg tier) -> no spill (watch WRITE_SIZE).
__global__ __launch_bounds__(512, 2) void attn(
    const unsigned short* __restrict__ q,
    const unsigned short* __restrict__ k,
    const unsigned short* __restrict__ vt,
    unsigned short* __restrict__ y)
{
    __shared__ unsigned short sk[2][2][64 * 64];   // [stage][parity][s][d], 32 KB
    __shared__ unsigned short sv[2][2][64 * 64];   // [stage][parity][d][s-perm]
    const int tid = threadIdx.x, wave = tid >> 6, lane = tid & 63;
    const int ws = wave & 3, wk2 = wave >> 2;      // q-slice, k-parity
    const int l15 = lane & 15, l4 = lane >> 4;
    const int bid = blockIdx.x;
    const int pr = bid >> 5;                       // 0..7 (pair index)
    const int bh = bid & 31;
    const int nb = bh >> 4, hh = bh & 15;
    const size_t base = (size_t)bh << 17;

    // staging: 8 waves x 8 rows cover all 64 rows of a tile in ONE gload16 call
    const int lrow = lane >> 3;                           // 0..7 local row
    const int gch = ((lane & 7) ^ lrow) << 3;             // swizzled chunk (elems)
    const int row = wave * 8 + lrow;                      // 0..63
    const unsigned short* kg = &k[base + (size_t)row * 64 + gch];
    const unsigned short* vg = &vt[(size_t)((hh << 6) + row) * 4096 + (nb << 11) + gch];
    const int lb = (wave * 8) * 64;                       // wave-uniform LDS base

    // read-side swizzled chunk offset for kf/vf (elements)
    const int rch0 = ((0 + l4) ^ (l15 & 7)) << 3;   // ks=0
    const int rch1 = ((4 + l4) ^ (l15 & 7)) << 3;   // ks=1

    // merge scratch views over the (then-dead) staging buffers
    float* mrg = (float*)&sk[0][0][0];              // 8192 floats = 32 KB (all of sk)
    float* lsr = (float*)&sv[0][0][0];
    const int mslot = (ws << 6) + lane;             // 0..255
    const int mb = mslot << 5;                      // 32 floats/thread

    auto process = [&](const int t) {               // t: 128-row tile 0..15
        const int q0 = t << 7;
        // Q fragments (B-operand: n=l15 -> q row, k=l4*8..+7 -> d);
        // group g covers q rows q0 + 64g + ws*16 + l15.
        bf16x8 qf[2][2];
        #pragma unroll
        for (int g = 0; g < 2; ++g)
            #pragma unroll
            for (int ks = 0; ks < 2; ++ks)
                qf[g][ks] = *(const bf16x8*)
                    &q[base + (size_t)(q0 + (g << 6) + ws * 16 + l15) * 64 + ks * 32 + l4 * 8];

        float l_sum[2] = {0.f, 0.f};
        f32x4 acc[2][4] = {};
        const int nsup = t + 1;                     // supersteps (k-tiles 0..2t+1)

        auto stage_pair = [&](const int sbuf, const int p) {
            gload16(kg + ((size_t)p << 13),        &sk[sbuf][0][lb]);  // k-tile 2p
            gload16(kg + ((size_t)p << 13) + 4096, &sk[sbuf][1][lb]);  // k-tile 2p+1
            gload16(vg + (p << 7),      &sv[sbuf][0][lb]);
            gload16(vg + (p << 7) + 64, &sv[sbuf][1][lb]);
        };

        stage_pair(0, 0);
        __syncthreads();

        // superstep body; LITERAL cur at call sites so LDS bases fold to imms
        auto sstep = [&](const int cur, const int p) {
            if (p + 1 < nsup) stage_pair(cur ^ 1, p + 1);
            const int st = 2 * p + wk2;
            const unsigned short* skc = &sk[cur][wk2][0];
            const unsigned short* svc = &sv[cur][wk2][0];

            f32x4 s_acc[2][4] = {};
            #pragma unroll
            for (int ns = 0; ns < 4; ++ns) {
                bf16x8 kf0 = *(const bf16x8*)&skc[(ns * 16 + l15) * 64 + rch0];
                bf16x8 kf1 = *(const bf16x8*)&skc[(ns * 16 + l15) * 64 + rch1];
                s_acc[0][ns] = MFMA_BF16(kf0, qf[0][0], s_acc[0][ns], 0, 0, 0);
                s_acc[0][ns] = MFMA_BF16(kf1, qf[0][1], s_acc[0][ns], 0, 0, 0);
                s_acc[1][ns] = MFMA_BF16(kf0, qf[1][0], s_acc[1][ns], 0, 0, 0);
                s_acc[1][ns] = MFMA_BF16(kf1, qf[1][1], s_acc[1][ns], 0, 0, 0);
            }

            // causal mask: only superstep p==t intersects the diagonal band.
            // global s = st*64 + ns*16 + l4*4 + r ; q = q0 + 64g + ws*16 + l15
            if (p == nsup - 1) {
                const int sb = st << 6;
                #pragma unroll
                for (int g = 0; g < 2; ++g) {
                    const int qlg = q0 + (g << 6) + ws * 16 + l15;
                    #pragma unroll
                    for (int ns = 0; ns < 4; ++ns)
                        #pragma unroll
                        for (int r = 0; r < 4; ++r)
                            if (sb + ns * 16 + l4 * 4 + r > qlg) s_acc[g][ns][r] = -1e30f;
                }
            }

            float pe[2][4][4];
            #pragma unroll
            for (int g = 0; g < 2; ++g)
                #pragma unroll
                for (int ns = 0; ns < 4; ++ns) {
                    #pragma unroll
                    for (int r = 0; r < 4; ++r) pe[g][ns][r] = exp2f(s_acc[g][ns][r]);
                    l_sum[g] += (pe[g][ns][0] + pe[g][ns][1]) + (pe[g][ns][2] + pe[g][ns][3]);
                }

            #pragma unroll
            for (int ks = 0; ks < 2; ++ks) {
                bf16x8 pf0, pf1;
                {
                    uint4 pw;
                    pw.x = pk2t(pe[0][2 * ks][0], pe[0][2 * ks][1]);
                    pw.y = pk2t(pe[0][2 * ks][2], pe[0][2 * ks][3]);
                    pw.z = pk2t(pe[0][2 * ks + 1][0], pe[0][2 * ks + 1][1]);
                    pw.w = pk2t(pe[0][2 * ks + 1][2], pe[0][2 * ks + 1][3]);
                    pf0 = *(bf16x8*)&pw;
                }
                {
                    uint4 pw;
                    pw.x = pk2t(pe[1][2 * ks][0], pe[1][2 * ks][1]);
                    pw.y = pk2t(pe[1][2 * ks][2], pe[1][2 * ks][3]);
                    pw.z = pk2t(pe[1][2 * ks + 1][0], pe[1][2 * ks + 1][1]);
                    pw.w = pk2t(pe[1][2 * ks + 1][2], pe[1][2 * ks + 1][3]);
                    pf1 = *(bf16x8*)&pw;
                }
                const int rch = ks ? rch1 : rch0;
                #pragma unroll
                for (int ds = 0; ds < 4; ++ds) {
                    bf16x8 vf = *(const bf16x8*)&svc[(ds * 16 + l15) * 64 + rch];
                    acc[0][ds] = MFMA_BF16(vf, pf0, acc[0][ds], 0, 0, 0);
                    acc[1][ds] = MFMA_BF16(vf, pf1, acc[1][ds], 0, 0, 0);
                }
            }
            __syncthreads();   // next pair's gload16 deposits flew during compute
        };

        int p = 0;
        for (; p + 2 <= nsup; p += 2) { sstep(0, p); sstep(1, p + 1); }
        if (p < nsup) sstep(0, p);

        // ---- cross-parity merge through LDS (exact f32 adds) ----
        if (wk2 == 1) {
            #pragma unroll
            for (int g = 0; g < 2; ++g)
                #pragma unroll
                for (int ds = 0; ds < 4; ++ds) {
                    const int c = g * 4 + ds;
                    *(f32x4*)&mrg[mb + ((c ^ (lane & 7)) << 2)] = acc[g][ds];
                }
            lsr[(mslot << 1) + 0] = l_sum[0];
            lsr[(mslot << 1) + 1] = l_sum[1];
        }
        __syncthreads();
        if (wk2 == 0) {
            #pragma unroll
            for (int g = 0; g < 2; ++g)
                #pragma unroll
                for (int ds = 0; ds < 4; ++ds) {
                    const int c = g * 4 + ds;
                    acc[g][ds] += *(const f32x4*)&mrg[mb + ((c ^ (lane & 7)) << 2)];
                }
            l_sum[0] += lsr[(mslot << 1) + 0];
            l_sum[1] += lsr[(mslot << 1) + 1];

            #pragma unroll
            for (int g = 0; g < 2; ++g) {
                float ls = l_sum[g];
                ls += __shfl_xor(ls, 16);
                ls += __shfl_xor(ls, 32);
                const float rl = __builtin_amdgcn_rcpf(ls);

                const size_t rowbase =
                    ((size_t)((nb << 11) + q0 + (g << 6) + ws * 16 + l15) << 10) + (hh << 6) + l4 * 4;
                #pragma unroll
                for (int ds = 0; ds < 4; ++ds) {
                    uint2 o;
                    o.x = pk2(acc[g][ds][0] * rl, acc[g][ds][1] * rl);
                    o.y = pk2(acc[g][ds][2] * rl, acc[g][ds][3] * rl);
                    *(uint2*)&y[rowbase + ds * 16] = o;
                }
            }
        }
        __syncthreads();   // merge reads done before next tile's staging reuses LDS
    };

    process(15 - pr);   // heavy tile first
    process(pr);        // complement: total supersteps = 17 for every block
}

extern "C" void kernel_launch(void* const* d_in, const int* in_sizes, int n_in,
                              void* d_out, int out_size, void* d_ws, size_t ws_size,
                              hipStream_t stream) {
    const float* x  = (const float*)d_in[0];
    const float* wq = (const float*)d_in[1];
    const float* wk = (const float*)d_in[2];
    const float* wv = (const float*)d_in[3];
    const float* wo = (const float*)d_in[4];
    float* out = (float*)d_out;

    const size_t M1 = 1u << 20;
    unsigned short* x16  = (unsigned short*)d_ws;          // 4M
    unsigned short* wq16 = x16 + 4 * M1;                   // 1M
    unsigned short* wk16 = wq16 + M1;
    unsigned short* wv16 = wk16 + M1;
    unsigned short* wot  = wv16 + M1;                      // 1M
    unsigned short* qbuf = wot + M1;                       // 4M [B,H,T,64]
    unsigned short* kbuf = qbuf + 4 * M1;                  // 4M
    unsigned short* vtb  = kbuf + 4 * M1;                  // 4M [1024][4096] sigma-perm
    unsigned short* ybuf = vtb + 4 * M1;                   // 4M [4096][1024]

    dim3 blk(256);
    prep<<<3840, blk, 0, stream>>>(x, wq, wk, wv, wo, x16, wq16, wk16, wv16, wot);
    proj<<<768, blk, 0, stream>>>(x16, wq16, wk16, wv16, qbuf, kbuf, vtb);
    attn<<<256, dim3(512), 0, stream>>>(qbuf, kbuf, vtb, ybuf);
    outp<<<256, blk, 0, stream>>>(ybuf, wot, out);
}